// Round 10
// baseline (994.104 us; speedup 1.0000x reference)
//
#include <hip/hip_runtime.h>
#include <hip/hip_cooperative_groups.h>

namespace cg = cooperative_groups;

// VQ-VAE vector quantizer, MI355X (gfx950).
// Round 15: single cooperative kernel. r14's six dispatches cost ~5 x ~14us
// of inter-dispatch drain/ramp (the "rest" pool was ~107us vs ~15us of actual
// non-argmin kernel work, invariant across r8-r14 restructurings). One
// vq_mega kernel, 1024 blocks x 256 thr (4 blocks/CU co-resident: 33KB LDS,
// VGPR<=128), grid.sync() between phases:
//   P0 prep -> P1 argmin (r14 verbatim) -> P2 pair+full fixups ->
//   P3 full-row resolve -> P4 gather rows<WSKIP + loss finalize.
// Fallback: if hipLaunchCooperativeKernel errors, launch the same phases as
// the measured-good r14 six-dispatch sequence (shared device functions).
//
// d_out scratch (bytes, consumed before P4 / overwritten later):
//   [0,524288) cbh_perm | [524288,786432) bv2a | [786432,1048576) bvfa
//   [1048576,1572864) ull minkey scratch | [1572864,1835008) flagf
// d_ws: [0,2048) double loss_slots[256]; [2048,2052) cnt2; [2052,2056) cntf;
//       [4096,8192) float Bf[1024]; [8192,270336) uint flag2 (n | seck<<16)

#define N_PTS    65536
#define K_CODES  1024
#define DIM      256
#define MARGIN   1.5e-4f
#define WSKIP    4096

#define OUT_VALS  16777216
#define OUT_CODES 65536

typedef __attribute__((ext_vector_type(8))) short short8v;
typedef __attribute__((ext_vector_type(8))) _Float16 half8v;
typedef __attribute__((ext_vector_type(4))) float float4v;

// perm index (in shorts) for codebook element (r=code, k=dim):
// chunk = ((r>>4)*8 + (k>>5))*4 + ((k>>3)&3); idx = chunk*128 + (r&15)*8 + (k&7)
__device__ __forceinline__ int perm_idx(int r, int k) {
  return ((((r >> 4) * 8 + (k >> 5)) * 4 + ((k >> 3) & 3)) * 128) + (r & 15) * 8 + (k & 7);
}

__device__ __forceinline__ short f2h_bits(float x) {
  union { _Float16 h; short s; } u;
  u.h = (_Float16)x;              // v_cvt_f16_f32, RTE
  return u.s;
}

__device__ __forceinline__ void gload16(const void* g, void* l) {
  __builtin_amdgcn_global_load_lds(
      (const __attribute__((address_space(1))) unsigned*)g,
      (__attribute__((address_space(3))) unsigned*)l, 16, 0, 0);
}

// ---------------- phases (shared by mega kernel and fallback) ----------------

// P0: block b preps code row b (wave 0); all threads init scratch/ws header.
__device__ __forceinline__ void phase_prep(int b, int t, const float* cb,
    short* cbh_perm, float* Bf, unsigned long long* scratch,
    unsigned long long* ws0) {
  const int gid = b * 256 + t;
  if (gid < 65536) scratch[gid] = ~0ull;      // minkeys
  if (gid < 512) ws0[gid] = 0ull;             // loss_slots + cnt2/cntf
  if (t < 64) {
    const float4 v = *(const float4*)(cb + (size_t)b * DIM + t * 4);
    double s = (double)v.x * v.x + (double)v.y * v.y
             + (double)v.z * v.z + (double)v.w * v.w;
#pragma unroll
    for (int off = 32; off > 0; off >>= 1) s += __shfl_down(s, off);
    if (t == 0) Bf[b] = (float)s;
    short4 h = make_short4(f2h_bits(v.x * 1024.0f), f2h_bits(v.y * 1024.0f),
                           f2h_bits(v.z * 1024.0f), f2h_bits(v.w * 1024.0f));
    *(short4*)(cbh_perm + perm_idx(b, t * 4)) = h;   // 8B aligned
  }
}

// P1: r14 argmin verbatim. Block b: 64 points x 1024 codes; wave w: 16 pts.
__device__ __forceinline__ void phase_argmin(int b, int t,
    short (*lbuf)[8192], double* wls,
    const float* z, const float* cb, const short* cbh_perm, const float* Bf,
    float* outq, float* codes_out, int* cnt2, int* cntf,
    unsigned* flag2, int* flagf, float* bv2a, float* bvfa,
    double* loss_slots) {
  const int w    = t >> 6;
  const int l    = t & 63;
  const int quad = l >> 4;
  const int lr   = l & 15;
  const int m0   = b * 64;

  // stage tile 0 early (latency hides under A-frag load/convert)
  {
    const char* src = (const char*)cbh_perm;
    char* dst = (char*)&lbuf[0][0];
#pragma unroll
    for (int i = 0; i < 4; ++i)
      gload16(src + t * 16 + i * 4096, dst + t * 16 + i * 4096);
  }

  // A-fragments + fp64 row sum of squares
  half8v ah[8];
  float Szrow;
  {
    const float* zrow = z + (size_t)(m0 + w * 16 + lr) * DIM;
    double zs0 = 0.0, zs1 = 0.0;
#pragma unroll
    for (int q = 0; q < 8; ++q) {
      float4 p0 = *(const float4*)(zrow + q * 32 + quad * 8);
      float4 p1 = *(const float4*)(zrow + q * 32 + quad * 8 + 4);
      zs0 = fma((double)p0.x, (double)p0.x, zs0);
      zs0 = fma((double)p0.y, (double)p0.y, zs0);
      zs0 = fma((double)p0.z, (double)p0.z, zs0);
      zs0 = fma((double)p0.w, (double)p0.w, zs0);
      zs1 = fma((double)p1.x, (double)p1.x, zs1);
      zs1 = fma((double)p1.y, (double)p1.y, zs1);
      zs1 = fma((double)p1.z, (double)p1.z, zs1);
      zs1 = fma((double)p1.w, (double)p1.w, zs1);
      half8v h;
      h[0] = (_Float16)p0.x; h[1] = (_Float16)p0.y;
      h[2] = (_Float16)p0.z; h[3] = (_Float16)p0.w;
      h[4] = (_Float16)p1.x; h[5] = (_Float16)p1.y;
      h[6] = (_Float16)p1.z; h[7] = (_Float16)p1.w;
      ah[q] = h;
    }
    double zs = zs0 + zs1;
    zs += __shfl_xor(zs, 16);
    zs += __shfl_xor(zs, 32);
    Szrow = (float)zs;             // ||z[m0 + w*16 + (l&15)]||^2
  }

  float bestv[4], secv[4], thirdv[4]; int bestk[4], seck[4];
#pragma unroll
  for (int r = 0; r < 4; ++r) {
    bestv[r] = 3.0e38f; secv[r] = 3.0e38f; thirdv[r] = 3.0e38f;
    bestk[r] = 0; seck[r] = 0;
  }

  __syncthreads();          // tile 0 resident (barrier drains vmcnt)
  int cur = 0;
  for (int it = 0; it < 32; ++it) {
    if (it < 31) {          // prefetch tile it+1 into the other buffer
      const char* src = (const char*)cbh_perm + (size_t)(it + 1) * 16384;
      char* dst = (char*)&lbuf[cur ^ 1][0];
#pragma unroll
      for (int i = 0; i < 4; ++i)
        gload16(src + t * 16 + i * 4096, dst + t * 16 + i * 4096);
    }
    const int c0 = it * 32;
#pragma unroll
    for (int st = 0; st < 2; ++st) {
      float4v acc = {0.f, 0.f, 0.f, 0.f};
#pragma unroll
      for (int q = 0; q < 8; ++q) {
        half8v bfr = *(const half8v*)(&lbuf[cur][(st * 8 + q) * 512 + quad * 128 + lr * 8]);
        acc = __builtin_amdgcn_mfma_f32_16x16x32_f16(ah[q], bfr, acc, 0, 0, 0);
      }
      const int k = c0 + st * 16 + lr;       // this lane's code (C col = lr)
      const float bkf = Bf[k];
#pragma unroll
      for (int r = 0; r < 4; ++r) {          // C row = quad*4 + r (point)
        float v = fmaf(-0.001953125f, acc[r], bkf);   // -2/1024, exact
        bool lt1 = v < bestv[r];
        bool lt2 = v < secv[r];
        thirdv[r] = fminf(fmaxf(v, secv[r]), thirdv[r]);   // med3
        secv[r]   = fminf(fmaxf(v, bestv[r]), secv[r]);    // med3
        bestv[r]  = fminf(v, bestv[r]);
        seck[r]   = lt1 ? bestk[r] : (lt2 ? k : seck[r]);
        bestk[r]  = lt1 ? k : bestk[r];
      }
    }
    __syncthreads();        // next tile landed; all readers done with cur
    cur ^= 1;
  }

  // top-3 merge across the 16 col-lanes of each quad (butterfly)
#pragma unroll
  for (int mask = 1; mask < 16; mask <<= 1) {
#pragma unroll
    for (int r = 0; r < 4; ++r) {
      float ov  = __shfl_xor(bestv[r], mask);
      float os  = __shfl_xor(secv[r], mask);
      float ot  = __shfl_xor(thirdv[r], mask);
      int   ok  = __shfl_xor(bestk[r], mask);
      int   osk = __shfl_xor(seck[r], mask);
      bool win = (ov < bestv[r]) || (ov == bestv[r] && ok < bestk[r]);
      float a1 = win ? ov : bestv[r], a2 = win ? os : secv[r], a3 = win ? ot : thirdv[r];
      int   a1k = win ? ok : bestk[r], a2k = win ? osk : seck[r];
      float b1 = win ? bestv[r] : ov, b2 = win ? secv[r] : os;
      int   b1k = win ? bestk[r] : ok;
      bool s2 = (a2 < b1) || (a2 == b1 && a2k < b1k);
      bestv[r] = a1; bestk[r] = a1k;
      secv[r] = s2 ? a2 : b1; seck[r] = s2 ? a2k : b1k;
      thirdv[r] = s2 ? fminf(a3, b1) : fminf(a2, b2);
    }
  }

  // per-slot row loss values (all lanes active: shfl outside divergence)
  float vrow[4];
#pragma unroll
  for (int r = 0; r < 4; ++r)
    vrow[r] = __shfl(Szrow, quad * 4 + r) + bestv[r];

  // fused quantized scatter (rows < WSKIP deferred: they overlap scratch)
  if (m0 >= WSKIP) {
#pragma unroll
    for (int p = 0; p < 16; ++p) {
      int c = __shfl(bestk[p & 3], (p >> 2) << 4);   // quad (p>>2), slot (p&3)
      int n = m0 + w * 16 + p;
      *(float4*)(outq + (size_t)n * DIM + l * 4) =
          *(const float4*)(cb + (size_t)c * DIM + l * 4);
    }
  }

  // fused loss: sum of vrow over the wave's 16 points
  double ls = 0.0;
  if (lr == 0)
    ls = (double)vrow[0] + (double)vrow[1] + (double)vrow[2] + (double)vrow[3];
  ls += __shfl_down(ls, 16);
  ls += __shfl_down(ls, 32);
  if (l == 0) wls[w] = ls;

  if (lr == 0) {
#pragma unroll
    for (int r = 0; r < 4; ++r) {
      int n = m0 + w * 16 + quad * 4 + r;
      codes_out[n] = (float)bestk[r];
      if (thirdv[r] - bestv[r] < MARGIN) {
        int pos = atomicAdd(cntf, 1);
        flagf[pos] = n; bvfa[pos] = vrow[r];
      } else if (secv[r] - bestv[r] < MARGIN) {
        int pos = atomicAdd(cnt2, 1);
        flag2[pos] = (unsigned)n | ((unsigned)seck[r] << 16);
        bv2a[pos] = vrow[r];
      }
    }
  }
  __syncthreads();
  if (t == 0)
    atomicAdd(&loss_slots[b & 255], wls[0] + wls[1] + wls[2] + wls[3]);
}

// P2a: pair fixup. One wave per flagged row; half-wave per candidate code.
// Exact emulation: v = fl32(fl32(Sfl + Bf[k]) - 2*fl32(dot64)); tie -> lower k.
__device__ __forceinline__ void phase_fixpair(int b, int t, int nb,
    const float* z, const float* cb, const float* Bf,
    const unsigned* flag2, const int* cnt2, const float* bv2a,
    float* codes_out, float* outq, double* loss_slots) {
  const int l   = t & 63;
  const int h   = l >> 5;
  const int sub = l & 31;
  const int wid = b * 4 + (t >> 6);
  const int nw  = nb * 4;
  const int cnt = *cnt2;
  for (int i = wid; i < cnt; i += nw) {
    const unsigned rec = flag2[i];
    const int n  = rec & 0xFFFF;
    const int k2 = rec >> 16;
    const int k1 = (int)codes_out[n];
    const int k  = h ? k2 : k1;
    const float* zr = z + (size_t)n * DIM + sub * 8;
    const float* cr = cb + (size_t)k * DIM + sub * 8;
    const float4 za = *(const float4*)(zr);
    const float4 zb = *(const float4*)(zr + 4);
    const float4 ca = *(const float4*)(cr);
    const float4 cv = *(const float4*)(cr + 4);
    double s = (double)za.x*za.x + (double)za.y*za.y + (double)za.z*za.z + (double)za.w*za.w
             + (double)zb.x*zb.x + (double)zb.y*zb.y + (double)zb.z*zb.z + (double)zb.w*zb.w;
    double d = (double)za.x*ca.x + (double)za.y*ca.y + (double)za.z*ca.z + (double)za.w*ca.w
             + (double)zb.x*cv.x + (double)zb.y*cv.y + (double)zb.z*cv.z + (double)zb.w*cv.w;
#pragma unroll
    for (int m = 1; m < 32; m <<= 1) {
      s += __shfl_xor(s, m);
      d += __shfl_xor(d, m);
    }
    const float Sfl = (float)s;
    const float T1  = Sfl + Bf[k];
    const float v   = T1 - 2.0f * (float)d;
    const float vo  = __shfl_xor(v, 32);
    const int   ko  = __shfl_xor(k, 32);
    const bool keep = (v < vo) || (v == vo && k < ko);
    const float vmin = keep ? v : vo;
    const int   kf   = keep ? k : ko;
    if (l == 0) {
      codes_out[n] = (float)kf;
      atomicAdd(&loss_slots[n & 255], (double)(vmin - bv2a[i]));
    }
    if (kf != k1 && n >= WSKIP)
      *(float4*)(outq + (size_t)n * DIM + l * 4) =
          *(const float4*)(cb + (size_t)kf * DIM + l * 4);
  }
}

// P2b: full rescan for 3+-candidate rows. 4 blocks/row (quarter q); wave =
// 64 codes; cross-block merge via atomicMin on (f32-bits<<32 | k) (v > 0).
__device__ __forceinline__ void phase_fixfull(int b, int t, int nb,
    float* vred, int* kred,
    const float* z, const float* cb, const float* Bf,
    const int* flagf, const int* cntf, unsigned long long* scratch) {
  const int w = t >> 6;
  const int l = t & 63;
  const int cnt = *cntf;
  for (int ib = b; (ib >> 2) < cnt; ib += nb) {
    const int i = ib >> 2, q = ib & 3;
    const int n = flagf[i];
    const float4 zv = *(const float4*)(z + (size_t)n * DIM + l * 4);
    double s = (double)zv.x*zv.x + (double)zv.y*zv.y
             + (double)zv.z*zv.z + (double)zv.w*zv.w;
#pragma unroll
    for (int off = 32; off > 0; off >>= 1) s += __shfl_xor(s, off);
    const float Sfl = (float)s;
    float bvv = 3.0e38f; int bkk = 0;
    const int kbase = q * 256 + w * 64;
#pragma unroll 4
    for (int k0 = 0; k0 < 64; ++k0) {
      const int k = kbase + k0;
      const float4 cv = *(const float4*)(cb + (size_t)k * DIM + l * 4);
      double d = (double)zv.x*cv.x + (double)zv.y*cv.y
               + (double)zv.z*cv.z + (double)zv.w*cv.w;
#pragma unroll
      for (int off = 32; off > 0; off >>= 1) d += __shfl_xor(d, off);
      float T1 = Sfl + Bf[k];
      float v  = T1 - 2.0f * (float)d;
      if (v < bvv) { bvv = v; bkk = k; }   // ascending k -> lowest on tie
    }
    __syncthreads();
    if (l == 0) { vred[w] = bvv; kred[w] = bkk; }
    __syncthreads();
    if (t == 0) {
      float fv = vred[0]; int fk = kred[0];
#pragma unroll
      for (int j = 1; j < 4; ++j) {
        float v2 = vred[j]; int kk = kred[j];
        if (v2 < fv || (v2 == fv && kk < fk)) { fv = v2; fk = kk; }
      }
      unsigned long long key =
          ((unsigned long long)__float_as_uint(fv) << 32) | (unsigned)fk;
      atomicMin(&scratch[n], key);
    }
  }
}

// P3: resolve full rows: wave per row; codes + loss delta + row rewrite.
__device__ __forceinline__ void phase_fixwrite(int b, int t, int nb,
    const int* flagf, const int* cntf, const unsigned long long* scratch,
    const float* bvfa, const float* cb,
    float* codes_out, float* outq, double* loss_slots) {
  const int l = t & 63;
  const int wid = b * 4 + (t >> 6);
  const int nw  = nb * 4;
  const int cnt = *cntf;
  for (int i = wid; i < cnt; i += nw) {
    const int n = flagf[i];
    const unsigned long long key = scratch[n];
    const int   fk = (int)(unsigned)(key & 0xFFFFFFFFull);
    const float fv = __uint_as_float((unsigned)(key >> 32));
    const int   k1 = (int)codes_out[n];
    if (l == 0) {
      codes_out[n] = (float)fk;
      atomicAdd(&loss_slots[n & 255], (double)(fv - bvfa[i]));
    }
    if (fk != k1 && n >= WSKIP)
      *(float4*)(outq + (size_t)n * DIM + l * 4) =
          *(const float4*)(cb + (size_t)fk * DIM + l * 4);
  }
}

// P4: gather rows [0, WSKIP) (scratch dead); block 0 finalizes loss.
// Requires nb == 1024 (4096 rows x 64 lanes = 262144 threads exactly).
__device__ __forceinline__ void phase_gatherfin(int b, int t, double* wred,
    const float* cb, const float* codes_out, float* outq,
    const double* loss_slots, float* out_loss) {
  const int gid = b * 256 + t;
  const int n = gid >> 6, l = gid & 63;
  const int c = (int)codes_out[n];
  *(float4*)(outq + (size_t)n * DIM + l * 4) =
      *(const float4*)(cb + (size_t)c * DIM + l * 4);
  if (b == 0) {
    double s = loss_slots[t];
#pragma unroll
    for (int off = 32; off > 0; off >>= 1) s += __shfl_down(s, off);
    if ((t & 63) == 0) wred[t >> 6] = s;
    __syncthreads();
    if (t == 0) {
      double tot = wred[0] + wred[1] + wred[2] + wred[3];
      out_loss[0] = (float)(1.25 * tot / (double)(N_PTS * (size_t)DIM));
    }
  }
}

// ---------------- mega kernel (cooperative, grid MUST be 1024x256) ----------

__global__ __launch_bounds__(256, 4) void vq_mega(
    const float* __restrict__ z, const float* __restrict__ cb,
    float* __restrict__ out, char* __restrict__ wsb) {
  __shared__ __align__(16) short lbuf[2][8192];   // 32 KB -> 4 blocks/CU
  __shared__ double wls[4];
  __shared__ float vred[4];
  __shared__ int   kred[4];
  double* loss_slots = (double*)wsb;
  int*      cnt2  = (int*)(wsb + 2048);
  int*      cntf  = (int*)(wsb + 2052);
  float*    Bf    = (float*)(wsb + 4096);
  unsigned* flag2 = (unsigned*)(wsb + 8192);
  short* cbh_perm = (short*)out;
  float* bv2a     = (float*)((char*)out + 524288);
  float* bvfa     = (float*)((char*)out + 786432);
  unsigned long long* scratch = (unsigned long long*)((char*)out + 1048576);
  int*   flagf    = (int*)((char*)out + 1572864);
  float* outq     = out;
  float* codes_out = out + OUT_VALS;
  float* out_loss  = out + OUT_VALS + OUT_CODES;

  const int b = blockIdx.x, t = threadIdx.x;
  cg::grid_group grid = cg::this_grid();

  phase_prep(b, t, cb, cbh_perm, Bf, scratch, (unsigned long long*)wsb);
  __threadfence(); grid.sync();

  phase_argmin(b, t, lbuf, wls, z, cb, cbh_perm, Bf, outq, codes_out,
               cnt2, cntf, flag2, flagf, bv2a, bvfa, loss_slots);
  __threadfence(); grid.sync();

  phase_fixpair(b, t, 1024, z, cb, Bf, flag2, cnt2, bv2a,
                codes_out, outq, loss_slots);
  phase_fixfull(b, t, 1024, vred, kred, z, cb, Bf, flagf, cntf, scratch);
  __threadfence(); grid.sync();

  phase_fixwrite(b, t, 1024, flagf, cntf, scratch, bvfa, cb,
                 codes_out, outq, loss_slots);
  __threadfence(); grid.sync();

  phase_gatherfin(b, t, wls, cb, codes_out, outq, loss_slots, out_loss);
}

// ---------------- fallback wrappers (r14 six-dispatch path) ------------------

__global__ void prep_cb_kernel(const float* __restrict__ cb,
                               short* __restrict__ cbh_perm,
                               float* __restrict__ Bf,
                               unsigned long long* __restrict__ scratch,
                               unsigned long long* __restrict__ ws0) {
  phase_prep(blockIdx.x, threadIdx.x, cb, cbh_perm, Bf, scratch, ws0);
}

__global__ __launch_bounds__(256, 4) void argmin_mfma_kernel(
    const float* __restrict__ z, const float* __restrict__ cb,
    const short* __restrict__ cbh_perm, const float* __restrict__ Bf,
    float* __restrict__ outq, float* __restrict__ codes_out,
    int* __restrict__ cnt2, int* __restrict__ cntf,
    unsigned* __restrict__ flag2, int* __restrict__ flagf,
    float* __restrict__ bv2a, float* __restrict__ bvfa,
    double* __restrict__ loss_slots) {
  __shared__ __align__(16) short lbuf[2][8192];
  __shared__ double wls[4];
  phase_argmin(blockIdx.x, threadIdx.x, lbuf, wls, z, cb, cbh_perm, Bf,
               outq, codes_out, cnt2, cntf, flag2, flagf, bv2a, bvfa,
               loss_slots);
}

__global__ __launch_bounds__(256) void fixup_pair_kernel(
    const float* __restrict__ z, const float* __restrict__ cb,
    const float* __restrict__ Bf, const unsigned* __restrict__ flag2,
    const int* __restrict__ cnt2, const float* __restrict__ bv2a,
    float* __restrict__ codes_out, float* __restrict__ outq,
    double* __restrict__ loss_slots) {
  phase_fixpair(blockIdx.x, threadIdx.x, gridDim.x, z, cb, Bf, flag2, cnt2,
                bv2a, codes_out, outq, loss_slots);
}

__global__ __launch_bounds__(256) void fixup_full_kernel(
    const float* __restrict__ z, const float* __restrict__ cb,
    const float* __restrict__ Bf, const int* __restrict__ flagf,
    const int* __restrict__ cntf, unsigned long long* __restrict__ scratch) {
  __shared__ float vred[4];
  __shared__ int   kred[4];
  phase_fixfull(blockIdx.x, threadIdx.x, gridDim.x, vred, kred,
                z, cb, Bf, flagf, cntf, scratch);
}

__global__ __launch_bounds__(256) void fixup_write_kernel(
    const int* __restrict__ flagf, const int* __restrict__ cntf,
    const unsigned long long* __restrict__ scratch,
    const float* __restrict__ bvfa, const float* __restrict__ cb,
    float* __restrict__ codes_out, float* __restrict__ outq,
    double* __restrict__ loss_slots) {
  phase_fixwrite(blockIdx.x, threadIdx.x, gridDim.x, flagf, cntf, scratch,
                 bvfa, cb, codes_out, outq, loss_slots);
}

__global__ void gather_finalize_kernel(const float* __restrict__ cb,
                                       const float* __restrict__ codes_f,
                                       float* __restrict__ outq,
                                       const double* __restrict__ loss_slots,
                                       float* __restrict__ out_loss) {
  __shared__ double wred[4];
  phase_gatherfin(blockIdx.x, threadIdx.x, wred, cb, codes_f, outq,
                  loss_slots, out_loss);
}

// ---------------- launcher ---------------------------------------------------

extern "C" void kernel_launch(void* const* d_in, const int* in_sizes, int n_in,
                              void* d_out, int out_size, void* d_ws, size_t ws_size,
                              hipStream_t stream) {
  const float* z  = (const float*)d_in[0];
  const float* cb = (const float*)d_in[1];
  float* out = (float*)d_out;
  char* wsb  = (char*)d_ws;

  void* kargs[] = {(void*)&z, (void*)&cb, (void*)&out, (void*)&wsb};
  hipError_t err = hipLaunchCooperativeKernel(
      (const void*)vq_mega, dim3(1024), dim3(256), kargs, 0, stream);
  if (err == hipSuccess) return;

  // fallback: measured-good r14 six-dispatch sequence (same phase code)
  double* loss_slots = (double*)wsb;
  int*      cnt2  = (int*)(wsb + 2048);
  int*      cntf  = (int*)(wsb + 2052);
  float*    Bf    = (float*)(wsb + 4096);
  unsigned* flag2 = (unsigned*)(wsb + 8192);
  short* cbh_perm = (short*)out;
  float* bv2a     = (float*)((char*)out + 524288);
  float* bvfa     = (float*)((char*)out + 786432);
  unsigned long long* scratch = (unsigned long long*)((char*)out + 1048576);
  int*   flagf    = (int*)((char*)out + 1572864);

  prep_cb_kernel<<<1024, 256, 0, stream>>>(
      cb, cbh_perm, Bf, scratch, (unsigned long long*)wsb);
  argmin_mfma_kernel<<<N_PTS / 64, 256, 0, stream>>>(
      z, cb, cbh_perm, Bf, out, out + OUT_VALS, cnt2, cntf, flag2, flagf,
      bv2a, bvfa, loss_slots);
  fixup_pair_kernel<<<1024, 256, 0, stream>>>(
      z, cb, Bf, flag2, cnt2, bv2a, out + OUT_VALS, out, loss_slots);
  fixup_full_kernel<<<2048, 256, 0, stream>>>(z, cb, Bf, flagf, cntf, scratch);
  fixup_write_kernel<<<64, 256, 0, stream>>>(
      flagf, cntf, scratch, bvfa, cb, out + OUT_VALS, out, loss_slots);
  gather_finalize_kernel<<<1024, 256, 0, stream>>>(
      cb, out + OUT_VALS, out, loss_slots, out + OUT_VALS + OUT_CODES);
}